// Round 1
// baseline (649.986 us; speedup 1.0000x reference)
//
#include <hip/hip_runtime.h>
#include <cstdint>

typedef unsigned int u32;
typedef _Float16 f16;
typedef _Float16 f16x4 __attribute__((ext_vector_type(4)));
typedef _Float16 f16x8 __attribute__((ext_vector_type(8)));
typedef float f32x4 __attribute__((ext_vector_type(4)));

#define DDIM 128

typedef __attribute__((address_space(1))) u32 gu32;
typedef __attribute__((address_space(3))) u32 lu32;

// async global->LDS, 16 B per lane. LDS dest must be wave-uniform base + lane*16.
__device__ __forceinline__ void direct16(const void* g, void* l) {
    __builtin_amdgcn_global_load_lds((gu32*)(uintptr_t)g, (lu32*)(uintptr_t)l, 16, 0, 0);
}

__device__ __forceinline__ float softplus_f(float x) {
    // stable: max(x,0) + log(1 + exp(-|x|))
    float ax = fabsf(x);
    float e  = __expf(-ax);
    return fmaxf(x, 0.0f) + __logf(1.0f + e);
}

// ---- kernel 1: convert inputs fp32 -> f16 ----
__global__ __launch_bounds__(256) void convx_kernel(const float* __restrict__ X, f16* __restrict__ Xb) {
    int t = blockIdx.x * 256 + threadIdx.x;        // B*D/4 threads
    float4 v = ((const float4*)X)[t];
    f16x4 h;
    h[0] = (f16)v.x; h[1] = (f16)v.y; h[2] = (f16)v.z; h[3] = (f16)v.w;
    ((f16x4*)Xb)[t] = h;
}

// ---- kernel 2: gather sampled rows -> f16, gather sampled biases ----
__global__ __launch_bounds__(256) void gather_kernel(const float* __restrict__ W, const float* __restrict__ bias,
                                                     const int* __restrict__ sids,
                                                     f16* __restrict__ Wb, float* __restrict__ bs) {
    int t = blockIdx.x * 256 + threadIdx.x;        // S*32 threads (32 float4 per row)
    int s = t >> 5, j = t & 31;
    int row = sids[s];
    float4 v = ((const float4*)(W + (size_t)row * DDIM))[j];
    f16x4 h;
    h[0] = (f16)v.x; h[1] = (f16)v.y; h[2] = (f16)v.z; h[3] = (f16)v.w;
    ((f16x4*)(Wb + (size_t)s * DDIM))[j] = h;
    if (j == 0) bs[s] = bias[row];
}

// ---- kernel 3: true-class term, fp32 exact; also initializes out[] ----
__global__ __launch_bounds__(256) void ce_true_kernel(const float* __restrict__ X, const float* __restrict__ W,
                                                      const float* __restrict__ bias, const int* __restrict__ tids,
                                                      float* __restrict__ out) {
    int gt = blockIdx.x * 256 + threadIdx.x;       // one wave per row
    int b = gt >> 6;
    int lane = gt & 63;
    int row = tids[b];
    float2 xv = ((const float2*)(X + (size_t)b   * DDIM))[lane];
    float2 wv = ((const float2*)(W + (size_t)row * DDIM))[lane];
    float d = fmaf(xv.x, wv.x, xv.y * wv.y);
#pragma unroll
    for (int off = 32; off > 0; off >>= 1) d += __shfl_xor(d, off);
    if (lane == 0) {
        float logit = d + bias[row];
        out[b] = softplus_f(-logit);               // plain store: initializes out
    }
}

// ---- kernel 4: fused GEMM (X * Wsamp^T) + bias + softplus + row-sum ----
// block tile 128(M) x 128(N), K=128 staged once. 4 waves in 2x2, each 64x64
// via 4x4 grid of 16x16x32 f16 MFMAs.
__global__ __launch_bounds__(256, 2) void nce_gemm(const f16* __restrict__ Xb, const f16* __restrict__ Wb,
                                                   const float* __restrict__ bs, float* __restrict__ out) {
    __shared__ __attribute__((aligned(16))) f16 As[128 * DDIM];   // 32 KB
    __shared__ __attribute__((aligned(16))) f16 Bs[128 * DDIM];   // 32 KB

    const int tid = threadIdx.x;
    const int bn = blockIdx.x, bm = blockIdx.y;

    // ---- stage both tiles with global_load_lds dwordx4 ----
    // LDS granule (m, g) holds global granule (g ^ (m&15)) of row m  -> XOR swizzle
    // kills the 256B-row-stride bank conflicts on ds_read_b128 (reads conflict-free
    // per 8-lane phase), while global side stays 4-full-row coalesced per inst.
    {
        const char* Ag = (const char*)(Xb + (size_t)bm * 128 * DDIM);
        const char* Bg = (const char*)(Wb + (size_t)bn * 128 * DDIM);
        int t4 = tid >> 4, t0 = tid & 15;
        int src0 = t4 * 256 + ((t0 ^ t4) << 4);
        int dst0 = tid << 4;
#pragma unroll
        for (int i = 0; i < 8; ++i) {
            direct16(Ag + i * 4096 + src0, (char*)As + i * 4096 + dst0);
            direct16(Bg + i * 4096 + src0, (char*)Bs + i * 4096 + dst0);
        }
    }
    __syncthreads();

    const int lane = tid & 63;
    const int w  = tid >> 6;
    const int wm = w >> 1, wn = w & 1;   // 2x2 wave grid
    const int l0 = lane & 15;            // fragment row (m) / col (n)
    const int q  = lane >> 4;            // k-quad

    f32x4 acc[4][4];
#pragma unroll
    for (int mi = 0; mi < 4; ++mi)
#pragma unroll
        for (int ni = 0; ni < 4; ++ni)
            acc[mi][ni] = (f32x4){0.f, 0.f, 0.f, 0.f};

#pragma unroll
    for (int ks = 0; ks < 4; ++ks) {
        f16x8 a_f[4], b_f[4];
        int g = ks * 4 + q;              // granule index along k (before swizzle)
#pragma unroll
        for (int mi = 0; mi < 4; ++mi) {
            int m_l = wm * 64 + mi * 16 + l0;
            a_f[mi] = *(const f16x8*)(As + m_l * DDIM + ((g ^ l0) << 3));
        }
#pragma unroll
        for (int ni = 0; ni < 4; ++ni) {
            int n_l = wn * 64 + ni * 16 + l0;
            b_f[ni] = *(const f16x8*)(Bs + n_l * DDIM + ((g ^ l0) << 3));
        }
#pragma unroll
        for (int mi = 0; mi < 4; ++mi)
#pragma unroll
            for (int ni = 0; ni < 4; ++ni)
                acc[mi][ni] = __builtin_amdgcn_mfma_f32_16x16x32_f16(a_f[mi], b_f[ni], acc[mi][ni], 0, 0, 0);
    }

    // ---- epilogue: softplus(logit + bias), reduce over n, atomicAdd per row ----
    // C/D layout (verified m89/m91): col = lane&15, row = (lane>>4)*4 + reg
    float bias_v[4];
#pragma unroll
    for (int ni = 0; ni < 4; ++ni)
        bias_v[ni] = bs[bn * 128 + wn * 64 + ni * 16 + l0];

#pragma unroll
    for (int mi = 0; mi < 4; ++mi) {
        float s0 = 0.f, s1 = 0.f, s2 = 0.f, s3 = 0.f;
#pragma unroll
        for (int ni = 0; ni < 4; ++ni) {
            f32x4 c = acc[mi][ni];
            float bv = bias_v[ni];
            s0 += softplus_f(c[0] + bv);
            s1 += softplus_f(c[1] + bv);
            s2 += softplus_f(c[2] + bv);
            s3 += softplus_f(c[3] + bv);
        }
        // reduce across the 16 columns (lanes sharing the same q)
#pragma unroll
        for (int off = 1; off < 16; off <<= 1) {
            s0 += __shfl_xor(s0, off);
            s1 += __shfl_xor(s1, off);
            s2 += __shfl_xor(s2, off);
            s3 += __shfl_xor(s3, off);
        }
        if (l0 == 0) {
            int m_g = bm * 128 + wm * 64 + mi * 16 + q * 4;
            atomicAdd(&out[m_g + 0], s0);
            atomicAdd(&out[m_g + 1], s1);
            atomicAdd(&out[m_g + 2], s2);
            atomicAdd(&out[m_g + 3], s3);
        }
    }
}

extern "C" void kernel_launch(void* const* d_in, const int* in_sizes, int n_in,
                              void* d_out, int out_size, void* d_ws, size_t ws_size,
                              hipStream_t stream) {
    const float* X  = (const float*)d_in[0];   // [8192,128] fp32
    const float* W  = (const float*)d_in[1];   // [1e6,128] fp32
    const float* Bv = (const float*)d_in[2];   // [1e6] fp32
    const int*   Ti = (const int*)d_in[3];     // [8192]
    const int*   Si = (const int*)d_in[4];     // [8192]
    float* out = (float*)d_out;                // [8192] fp32

    // workspace layout: Xb f16 2MB | Wb f16 2MB | bs f32 32KB
    f16*   Xb = (f16*)d_ws;
    f16*   Wb = (f16*)((char*)d_ws + (2u << 20));
    float* bs = (float*)((char*)d_ws + (4u << 20));

    convx_kernel <<<1024, 256, 0, stream>>>(X, Xb);              // 8192*128/4 threads
    gather_kernel<<<1024, 256, 0, stream>>>(W, Bv, Si, Wb, bs);  // 8192*32 threads
    ce_true_kernel<<<2048, 256, 0, stream>>>(X, W, Bv, Ti, out); // wave per row
    nce_gemm<<<dim3(64, 64), 256, 0, stream>>>(Xb, Wb, bs, out);
}

// Round 2
// 593.667 us; speedup vs baseline: 1.0949x; 1.0949x over previous
//
#include <hip/hip_runtime.h>
#include <cstdint>

typedef unsigned int u32;
typedef _Float16 f16;
typedef _Float16 f16x4 __attribute__((ext_vector_type(4)));
typedef _Float16 f16x8 __attribute__((ext_vector_type(8)));
typedef float f32x4 __attribute__((ext_vector_type(4)));

#define DDIM 128
#define NBN 64          // S / 128
#define LOG2E 1.4426950408889634f
#define LN2   0.6931471805599453f

typedef __attribute__((address_space(1))) u32 gu32;
typedef __attribute__((address_space(3))) u32 lu32;

// async global->LDS, 16 B per lane. LDS dest must be wave-uniform base + lane*16.
__device__ __forceinline__ void direct16(const void* g, void* l) {
    __builtin_amdgcn_global_load_lds((gu32*)(uintptr_t)g, (lu32*)(uintptr_t)l, 16, 0, 0);
}

__device__ __forceinline__ float softplus_exact(float x) {
    float ax = fabsf(x);
    float e  = __expf(-ax);
    return fmaxf(x, 0.0f) + __logf(1.0f + e);
}

// ---- kernel 1: prep. blocks [0,1024): X fp32->f16. blocks [1024,2048): gather W rows ----
__global__ __launch_bounds__(256) void prep_kernel(const float* __restrict__ X, f16* __restrict__ Xb,
                                                   const float* __restrict__ W, const float* __restrict__ bias,
                                                   const int* __restrict__ sids,
                                                   f16* __restrict__ Wb, float* __restrict__ bs) {
    if (blockIdx.x < 1024) {
        int t = blockIdx.x * 256 + threadIdx.x;        // B*D/4 threads
        float4 v = ((const float4*)X)[t];
        f16x4 h;
        h[0] = (f16)v.x; h[1] = (f16)v.y; h[2] = (f16)v.z; h[3] = (f16)v.w;
        ((f16x4*)Xb)[t] = h;
    } else {
        int t = (blockIdx.x - 1024) * 256 + threadIdx.x; // S*32 threads (32 float4 per row)
        int s = t >> 5, j = t & 31;
        int row = sids[s];
        float4 v = ((const float4*)(W + (size_t)row * DDIM))[j];
        f16x4 h;
        h[0] = (f16)v.x; h[1] = (f16)v.y; h[2] = (f16)v.z; h[3] = (f16)v.w;
        ((f16x4*)(Wb + (size_t)s * DDIM))[j] = h;
        if (j == 0) bs[s] = bias[row];
    }
}

// ---- kernel 2: true-class term, fp32 exact; initializes out[] ----
__global__ __launch_bounds__(256) void ce_true_kernel(const float* __restrict__ X, const float* __restrict__ W,
                                                      const float* __restrict__ bias, const int* __restrict__ tids,
                                                      float* __restrict__ out) {
    int gt = blockIdx.x * 256 + threadIdx.x;       // one wave per row
    int b = gt >> 6;
    int lane = gt & 63;
    int row = tids[b];
    float2 xv = ((const float2*)(X + (size_t)b   * DDIM))[lane];
    float2 wv = ((const float2*)(W + (size_t)row * DDIM))[lane];
    float d = fmaf(xv.x, wv.x, xv.y * wv.y);
#pragma unroll
    for (int off = 32; off > 0; off >>= 1) d += __shfl_xor(d, off);
    if (lane == 0) {
        float logit = d + bias[row];
        out[b] = softplus_exact(-logit);           // plain store: initializes out
    }
}

// ---- kernel 3: fused GEMM (X * Wsamp^T) + bias + softplus + row-sum -> partial[bn][m] ----
// 128x128 tile, K=128 staged once. 4 waves stacked on M (each 32 rows x ALL 128 cols),
// so every output row reduces entirely within one wave: no atomics, no LDS epilogue.
__global__ __launch_bounds__(256, 2) void nce_gemm(const f16* __restrict__ Xb, const f16* __restrict__ Wb,
                                                   const float* __restrict__ bs, float* __restrict__ partial) {
    __shared__ __attribute__((aligned(16))) f16 As[128 * DDIM];   // 32 KB
    __shared__ __attribute__((aligned(16))) f16 Bs[128 * DDIM];   // 32 KB

    const int tid = threadIdx.x;
    const int bn = blockIdx.x, bm = blockIdx.y;

    // stage both tiles via global_load_lds dwordx4 with XOR-swizzled source granules:
    // LDS granule (m, g) holds global granule (g ^ (m&15)) of row m -> conflict-free
    // ds_read_b128 later; global side stays 4-row/1KB coalesced per instruction.
    {
        const char* Ag = (const char*)(Xb + (size_t)bm * 128 * DDIM);
        const char* Bg = (const char*)(Wb + (size_t)bn * 128 * DDIM);
        int t4 = tid >> 4, t0 = tid & 15;
        int src0 = t4 * 256 + ((t0 ^ t4) << 4);
        int dst0 = tid << 4;
#pragma unroll
        for (int i = 0; i < 8; ++i) {
            direct16(Ag + i * 4096 + src0, (char*)As + i * 4096 + dst0);
            direct16(Bg + i * 4096 + src0, (char*)Bs + i * 4096 + dst0);
        }
    }
    __syncthreads();

    const int lane = tid & 63;
    const int w  = tid >> 6;             // wave id: rows [w*32, w*32+32)
    const int l0 = lane & 15;            // fragment row (m) / col (n)
    const int q  = lane >> 4;            // k-quad

    f32x4 acc[2][8];
#pragma unroll
    for (int mi = 0; mi < 2; ++mi)
#pragma unroll
        for (int ni = 0; ni < 8; ++ni)
            acc[mi][ni] = (f32x4){0.f, 0.f, 0.f, 0.f};

#pragma unroll
    for (int ks = 0; ks < 4; ++ks) {
        f16x8 a_f[2], b_f[8];
        int g = ks * 4 + q;              // k-granule (before swizzle)
#pragma unroll
        for (int mi = 0; mi < 2; ++mi) {
            int m_l = w * 32 + mi * 16 + l0;
            a_f[mi] = *(const f16x8*)(As + m_l * DDIM + ((g ^ l0) << 3));
        }
#pragma unroll
        for (int ni = 0; ni < 8; ++ni) {
            int n_l = ni * 16 + l0;
            b_f[ni] = *(const f16x8*)(Bs + n_l * DDIM + ((g ^ l0) << 3));
        }
#pragma unroll
        for (int mi = 0; mi < 2; ++mi)
#pragma unroll
            for (int ni = 0; ni < 8; ++ni)
                acc[mi][ni] = __builtin_amdgcn_mfma_f32_16x16x32_f16(a_f[mi], b_f[ni], acc[mi][ni], 0, 0, 0);
    }

    // epilogue in log2 domain: sum softplus(c+b) = ln2 * sum[ max(t,0) + log2(1+2^-|t|) ],
    // t = (c+b)*log2e. The *ln2 is deferred to once per row-sum; -|t| folds into v_exp_f32.
    // C/D layout: col = lane&15, row = q*4 + reg.
    float bt[8];
#pragma unroll
    for (int ni = 0; ni < 8; ++ni)
        bt[ni] = bs[bn * 128 + ni * 16 + l0] * LOG2E;

#pragma unroll
    for (int mi = 0; mi < 2; ++mi) {
        float s0 = 0.f, s1 = 0.f, s2 = 0.f, s3 = 0.f;
#pragma unroll
        for (int ni = 0; ni < 8; ++ni) {
            f32x4 c = acc[mi][ni];
            float bv = bt[ni];
            float t0 = fmaf(c[0], LOG2E, bv);
            float t1 = fmaf(c[1], LOG2E, bv);
            float t2 = fmaf(c[2], LOG2E, bv);
            float t3 = fmaf(c[3], LOG2E, bv);
            s0 += fmaxf(t0, 0.f) + __builtin_amdgcn_logf(1.f + __builtin_amdgcn_exp2f(-fabsf(t0)));
            s1 += fmaxf(t1, 0.f) + __builtin_amdgcn_logf(1.f + __builtin_amdgcn_exp2f(-fabsf(t1)));
            s2 += fmaxf(t2, 0.f) + __builtin_amdgcn_logf(1.f + __builtin_amdgcn_exp2f(-fabsf(t2)));
            s3 += fmaxf(t3, 0.f) + __builtin_amdgcn_logf(1.f + __builtin_amdgcn_exp2f(-fabsf(t3)));
        }
        // reduce across the 16 column-lanes (same q)
#pragma unroll
        for (int off = 1; off < 16; off <<= 1) {
            s0 += __shfl_xor(s0, off);
            s1 += __shfl_xor(s1, off);
            s2 += __shfl_xor(s2, off);
            s3 += __shfl_xor(s3, off);
        }
        if (l0 == 0) {
            int m = bm * 128 + w * 32 + mi * 16 + q * 4;
            float4 v = make_float4(s0 * LN2, s1 * LN2, s2 * LN2, s3 * LN2);
            *(float4*)(partial + (size_t)bn * 8192 + m) = v;   // unique -> plain store
        }
    }
}

// ---- kernel 4: fold 64 deterministic partials into out (out already holds ce_true) ----
__global__ __launch_bounds__(256) void reduce_kernel(const float* __restrict__ partial, float* __restrict__ out) {
    int t = blockIdx.x * 256 + threadIdx.x;        // 2048 threads, float4 each
    float4 s = ((const float4*)out)[t];            // ce_true term
#pragma unroll
    for (int bn = 0; bn < NBN; ++bn) {
        float4 p = ((const float4*)(partial + (size_t)bn * 8192))[t];
        s.x += p.x; s.y += p.y; s.z += p.z; s.w += p.w;
    }
    ((float4*)out)[t] = s;
}

extern "C" void kernel_launch(void* const* d_in, const int* in_sizes, int n_in,
                              void* d_out, int out_size, void* d_ws, size_t ws_size,
                              hipStream_t stream) {
    const float* X  = (const float*)d_in[0];   // [8192,128] fp32
    const float* W  = (const float*)d_in[1];   // [1e6,128] fp32
    const float* Bv = (const float*)d_in[2];   // [1e6] fp32
    const int*   Ti = (const int*)d_in[3];     // [8192]
    const int*   Si = (const int*)d_in[4];     // [8192]
    float* out = (float*)d_out;                // [8192] fp32

    // ws: Xb f16 2MB | Wb f16 2MB | bs f32 32KB | partial f32 2MB @5MB
    f16*   Xb = (f16*)d_ws;
    f16*   Wb = (f16*)((char*)d_ws + (2u << 20));
    float* bs = (float*)((char*)d_ws + (4u << 20));
    float* pp = (float*)((char*)d_ws + (5u << 20));

    prep_kernel   <<<2048, 256, 0, stream>>>(X, Xb, W, Bv, Si, Wb, bs);
    ce_true_kernel<<<2048, 256, 0, stream>>>(X, W, Bv, Ti, out);
    nce_gemm      <<<dim3(64, 64), 256, 0, stream>>>(Xb, Wb, bs, pp);
    reduce_kernel <<<8, 256, 0, stream>>>(pp, out);
}